// Round 3
// baseline (326.982 us; speedup 1.0000x reference)
//
#include <hip/hip_runtime.h>
#include <math.h>

#define LMAX 8
#define NCOEF 45   // (LMAX+1)*(LMAX+2)/2
#define NY 81      // (LMAX+1)^2

// Native clang vector: __builtin_nontemporal_store rejects HIP_vector_type
// (class), but accepts ext_vector_type.
typedef float f4 __attribute__((ext_vector_type(4)));

struct Coefs { float c[NCOEF]; };

// 256 threads, min 6 blocks/CU (24 waves/CU) -> VGPR cap 85. Natural pressure
// after dropping band[] should be ~60, so the bound is slack, not spill-forcing.
__global__ __launch_bounds__(256, 6) void sph_kernel(const float* __restrict__ R,
                                                     float* __restrict__ out,
                                                     int N, Coefs cf) {
    // One LDS slice per wave: 64 points x 17 (max 2l+1) floats, 16B-aligned so
    // the float4 flush is legal. Single buffer: DS ops are in-order per wave,
    // so flush reads of band l are ordered before the writes of band l+1
    // automatically (no __syncthreads, no double buffer, no WAR hazard).
    __shared__ __align__(16) float lds[4][64 * 17];

    const int tid  = threadIdx.x;
    const int wave = tid >> 6;
    const int lane = tid & 63;
    const int i    = blockIdx.x * 256 + tid;
    const int wave_base = blockIdx.x * 256 + wave * 64;

    // Load direction (safe defaults for out-of-range lanes: unit z).
    float x = 0.0f, y = 0.0f, z = 1.0f;
    if (i < N) {
        x = R[3 * i + 0];
        y = R[3 * i + 1];
        z = R[3 * i + 2];
    }
    float rinv = 1.0f / sqrtf(x * x + y * y + z * z);
    x *= rinv; y *= rinv; z *= rinv;

    // Valid points in this wave (N may not be a multiple of 64).
    int cnt = N - wave_base;
    if (cnt > 64) cnt = 64;
    if (cnt < 0)  cnt = 0;

    float* sl = &lds[wave][0];

    // l-outer recurrence ladders: per-m state only (~36 VGPR), values are
    // written through to LDS the moment they are produced (no band[] array).
    float A[LMAX + 1], B[LMAX + 1], P1[LMAX + 1], P2[LMAX + 1];
    A[0] = 1.0f; B[0] = 0.0f;

    #pragma unroll
    for (int l = 0; l <= LMAX; ++l) {
        if (l > 0) {
            A[l] = x * A[l - 1] - y * B[l - 1];
            B[l] = x * B[l - 1] + y * A[l - 1];
        }
        const int w = 2 * l + 1;
        float* slr = sl + lane * w;        // odd stride -> conflict-free banks

        #pragma unroll
        for (int m = 0; m <= l; ++m) {
            float p;
            if (m == l) {
                float pmm = 1.0f;                      // (2l-1)!! — compile-time
                #pragma unroll
                for (int k = 1; k < 2 * l; k += 2) pmm *= (float)k;
                p = pmm;
                P2[m] = 0.0f;
            } else if (m == l - 1) {
                p = (2.0f * (float)l - 1.0f) * z * P1[m];
                P2[m] = P1[m];
            } else {
                float o1 = P1[m];
                p = ((2.0f * (float)l - 1.0f) * z * o1 - (float)(l + m - 1) * P2[m])
                    * (1.0f / (float)(l - m));         // 1/(l-m) folds to constant
                P2[m] = o1;
            }
            P1[m] = p;
            float np = cf.c[l * (l + 1) / 2 + m] * p;  // constant index after unroll
            if (m == 0) {
                slr[l] = np;                           // ds_write_b32, const offset
            } else {
                slr[l + m] = np * A[m];
                slr[l - m] = np * B[m];
            }
        }

        // Flush this wave's 64 x w tile: 16*w float4s, fully coalesced,
        // nontemporal (output is write-once, never re-read).
        const size_t region = (size_t)N * (size_t)(l * l)
                            + (size_t)wave_base * (size_t)w;
        if (cnt == 64 && ((region & 3) == 0)) {
            f4* __restrict__ out4 = (f4*)(out + region);
            const f4* sl4 = (const f4*)sl;
            #pragma unroll
            for (int t = lane; t < 16 * w; t += 64)
                __builtin_nontemporal_store(sl4[t], &out4[t]);
        } else {
            // Tail wave: scalar, still coalesced.
            for (int t = lane; t < cnt * w; t += 64)
                out[region + t] = sl[t];
        }
    }
}

extern "C" void kernel_launch(void* const* d_in, const int* in_sizes, int n_in,
                              void* d_out, int out_size, void* d_ws, size_t ws_size,
                              hipStream_t stream) {
    const float* R = (const float*)d_in[0];
    float* out = (float*)d_out;
    int N = in_sizes[0] / 3;

    // Norms in l-outer order to match device indexing: idx = l*(l+1)/2 + m.
    Coefs cf;
    for (int l = 0; l <= LMAX; ++l) {
        for (int m = 0; m <= l; ++m) {
            double fr = 1.0;
            for (int k = l - m + 1; k <= l + m; ++k) fr *= (double)k;
            double norm = sqrt((double)(2 * l + 1) / (4.0 * M_PI) / fr);
            if (m > 0) norm *= sqrt(2.0);
            cf.c[l * (l + 1) / 2 + m] = (float)norm;
        }
    }

    int blocks = (N + 255) / 256;
    sph_kernel<<<blocks, 256, 0, stream>>>(R, out, N, cf);
}